// Round 10
// baseline (40904.556 us; speedup 1.0000x reference)
//
#include <hip/hip_runtime.h>

#define TT 2048
#define BB 32
#define DD 512
#define HH 512
#define NWG 64
#define NTHR 256

typedef short s8v __attribute__((ext_vector_type(8)));
typedef float f4v __attribute__((ext_vector_type(4)));
typedef unsigned u4v __attribute__((ext_vector_type(4)));

union UF { u4v u; s8v s; };

__device__ __forceinline__ float asf(unsigned u) { return __uint_as_float(u); }

// v_cvt_pk_bf16_f32: D[15:0]=bf16(a) RNE, D[31:16]=bf16(b)
__device__ __forceinline__ unsigned cvtpk(float a, float b) {
    unsigned r;
    asm("v_cvt_pk_bf16_f32 %0, %1, %2" : "=v"(r) : "v"(a), "v"(b));
    return r;
}
// split pair (a,b) -> hi-packed u32 and lo-packed u32 (a ~= hi+lo to ~2^-16 rel)
__device__ __forceinline__ void split2(float a, float b, unsigned& hp, unsigned& lp) {
    hp = cvtpk(a, b);
    lp = cvtpk(a - asf(hp << 16), b - asf(hp & 0xFFFF0000u));
}

// ws layout (u32 units): hhi[2][BB*HH/2] | hlo[2][BB*HH/2] | flags[NWG*16]
__global__ void lstm_init(const float* __restrict__ h0,
                          unsigned* __restrict__ hhi,
                          unsigned* __restrict__ hlo,
                          unsigned* __restrict__ flags) {
    int j = blockIdx.x * blockDim.x + threadIdx.x;
    if (j < NWG * 16) flags[j] = 0u;
    if (j < BB * HH / 2) {
        unsigned hp, lp;
        split2(h0[2 * j], h0[2 * j + 1], hp, lp);
        hhi[j] = hp;   // buffer 0 (t=0); kernel-boundary sync makes this visible
        hlo[j] = lp;
    }
}

__global__ __launch_bounds__(NTHR, 1) void lstm_scan(
    const float* __restrict__ x,     // [B][T][D] f32
    const float* __restrict__ W,     // [1024][2048] f32 (rows 0..511 Wx, 512..1023 Wh)
    const float* __restrict__ bias,  // [2048] f32 (i|f|g|o)
    const float* __restrict__ c0,    // [B][H] f32
    float* __restrict__ out,         // f32: outputs[B][T][H] | h_T[B][H] | c_T[B][H]
    unsigned* hhi, unsigned* hlo,    // packed bf16-pair h buffers (cross-WG shared)
    unsigned* flags)
{
    __shared__ float P[32][33];      // gates exchange: [batch][gatecol], gatecol = q*8+unit

    const int wg  = blockIdx.x;      // owns hidden units u0..u0+7
    const int tid = threadIdx.x;
    const int u0  = wg * 8;
    const int wv  = tid >> 6, ln = tid & 63;
    const int bh  = wv >> 1;         // batch half: A rows bh*16..+15
    const int ch  = wv & 1;          // gate-col half: B cols ch*16..+15
    const int fl  = ln & 15;         // A row / B col within 16
    const int fg  = ln >> 4;         // k-group: k = it*32 + fg*8 + j

    // ---- one-time: weight slice -> registers as RNE hi/lo bf16 fragments
    s8v whi[32], wlo[32];
    {
        const int col  = ch * 16 + fl;                       // P col 0..31
        const int wcol = ((col >> 3) << 9) + u0 + (col & 7); // gate*512 + unit
        #pragma unroll
        for (int it = 0; it < 32; ++it) {
            float v[8];
            #pragma unroll
            for (int j = 0; j < 8; ++j)
                v[j] = W[(size_t)(it * 32 + fg * 8 + j) * 2048 + wcol];
            UF H, L;
            #pragma unroll
            for (int q = 0; q < 4; ++q) {
                unsigned hp, lp;
                split2(v[2 * q], v[2 * q + 1], hp, lp);
                H.u[q] = hp; L.u[q] = lp;
            }
            whi[it] = H.s; wlo[it] = L.s;
        }
    }

    // ---- cell ownership: (batch em, unit u0+ei)
    const int em = tid >> 3, ei = tid & 7;
    const float bI = bias[u0 + ei];
    const float bF = bias[HH + u0 + ei];
    const float bG = bias[2 * HH + u0 + ei];
    const float bO = bias[3 * HH + u0 + ei];
    float cst = c0[em * HH + u0 + ei];

    const int arow = bh * 16 + fl;                     // batch row this lane loads
    const float* xlane = x + (size_t)arow * TT * DD + fg * 8;
    const int hb = arow * (HH / 2) + fg * 4;           // u32 base into h buffers

    for (int t = 0; t < TT; ++t) {
        f4v acc  = {0.f, 0.f, 0.f, 0.f};
        f4v accl = {0.f, 0.f, 0.f, 0.f};

        // ---- x contribution: HOIST all 32 loads (one pipelined latency), then cvt+MFMA
        {
            const float* xs = xlane + (size_t)t * DD;
            float4 xf[32];
            #pragma unroll
            for (int it = 0; it < 16; ++it) {
                xf[2 * it]     = *(const float4*)(xs + it * 32);
                xf[2 * it + 1] = *(const float4*)(xs + it * 32 + 4);
            }
            #pragma unroll
            for (int it = 0; it < 16; ++it) {
                float4 f0 = xf[2 * it], f1 = xf[2 * it + 1];
                UF H, L;
                unsigned hp, lp;
                split2(f0.x, f0.y, hp, lp); H.u[0] = hp; L.u[0] = lp;
                split2(f0.z, f0.w, hp, lp); H.u[1] = hp; L.u[1] = lp;
                split2(f1.x, f1.y, hp, lp); H.u[2] = hp; L.u[2] = lp;
                split2(f1.z, f1.w, hp, lp); H.u[3] = hp; L.u[3] = lp;
                acc  = __builtin_amdgcn_mfma_f32_16x16x32_bf16(H.s, whi[it], acc, 0, 0, 0);
                accl = __builtin_amdgcn_mfma_f32_16x16x32_bf16(L.s, whi[it], accl, 0, 0, 0);
                accl = __builtin_amdgcn_mfma_f32_16x16x32_bf16(H.s, wlo[it], accl, 0, 0, 0);
            }
        }

        // ---- wait for h_t from all WGs (t=0: init kernel, kernel-boundary sync)
        if (t > 0) {
            if (tid < 64) {
                for (;;) {
                    unsigned v = __hip_atomic_load(&flags[tid * 16], __ATOMIC_RELAXED,
                                                   __HIP_MEMORY_SCOPE_AGENT);
                    if (__all((int)v >= t)) break;
                }
            }
            __syncthreads();
            // no acquire fence: h loads below are agent-scope atomics (coherence-point reads)
        }

        // ---- h contribution: 128 relaxed agent atomic dword loads, hoisted, then MFMA
        {
            const unsigned* hh = hhi + (size_t)(t & 1) * (BB * HH / 2);
            const unsigned* hl = hlo + (size_t)(t & 1) * (BB * HH / 2);
            unsigned hbu[64], lbu[64];
            #pragma unroll
            for (int it = 0; it < 16; ++it) {
                #pragma unroll
                for (int q = 0; q < 4; ++q) {
                    hbu[it * 4 + q] = __hip_atomic_load(&hh[hb + it * 16 + q],
                                                        __ATOMIC_RELAXED, __HIP_MEMORY_SCOPE_AGENT);
                    lbu[it * 4 + q] = __hip_atomic_load(&hl[hb + it * 16 + q],
                                                        __ATOMIC_RELAXED, __HIP_MEMORY_SCOPE_AGENT);
                }
            }
            #pragma unroll
            for (int it = 0; it < 16; ++it) {
                UF H, L;
                #pragma unroll
                for (int q = 0; q < 4; ++q) { H.u[q] = hbu[it * 4 + q]; L.u[q] = lbu[it * 4 + q]; }
                acc  = __builtin_amdgcn_mfma_f32_16x16x32_bf16(H.s, whi[16 + it], acc, 0, 0, 0);
                accl = __builtin_amdgcn_mfma_f32_16x16x32_bf16(L.s, whi[16 + it], accl, 0, 0, 0);
                accl = __builtin_amdgcn_mfma_f32_16x16x32_bf16(H.s, wlo[16 + it], accl, 0, 0, 0);
            }
        }

        // ---- C write: col=lane&15, row=(lane>>4)*4+reg (m89/m91-verified)
        #pragma unroll
        for (int r = 0; r < 4; ++r)
            P[bh * 16 + fg * 4 + r][ch * 16 + fl] = acc[r] + accl[r];
        __syncthreads();

        // ---- elementwise LSTM cell
        float gi = bI + P[em][ei];
        float gf = bF + P[em][8 + ei];
        float gg = bG + P[em][16 + ei];
        float go = bO + P[em][24 + ei];
        float si = 1.0f / (1.0f + __expf(-gi));
        float sf = 1.0f / (1.0f + __expf(-gf));
        float e2 = __expf(2.0f * fminf(fmaxf(gg, -15.f), 15.f));
        float tg = (e2 - 1.0f) / (e2 + 1.0f);
        float so = 1.0f / (1.0f + __expf(-go));
        cst = sf * cst + si * tg;
        float e2c = __expf(2.0f * fminf(fmaxf(cst, -15.f), 15.f));
        float h = so * (e2c - 1.0f) / (e2c + 1.0f);

        // ---- publish h_{t+1} FIRST (critical path), outputs after
        {
            float hn = __shfl_down(h, 1);
            if ((ei & 1) == 0) {
                unsigned hp, lp;
                split2(h, hn, hp, lp);
                int idx = em * (HH / 2) + ((u0 + ei) >> 1);
                unsigned* dh = hhi + (size_t)((t + 1) & 1) * (BB * HH / 2);
                unsigned* dl = hlo + (size_t)((t + 1) & 1) * (BB * HH / 2);
                __hip_atomic_store(&dh[idx], hp, __ATOMIC_RELAXED, __HIP_MEMORY_SCOPE_AGENT);
                __hip_atomic_store(&dl[idx], lp, __ATOMIC_RELAXED, __HIP_MEMORY_SCOPE_AGENT);
            }
        }
        __syncthreads();   // per-wave vmcnt(0) drain: h stores committed at LLC
        if (tid == 0)
            __hip_atomic_store(&flags[wg * 16], (unsigned)(t + 1),
                               __ATOMIC_RELAXED, __HIP_MEMORY_SCOPE_AGENT);

        // ---- outputs (f32, [B][T][H]) — off the inter-WG critical path
        out[(size_t)em * TT * HH + (size_t)t * HH + u0 + ei] = h;
        if (t == TT - 1) {
            size_t ho = (size_t)BB * TT * HH;
            out[ho + em * HH + u0 + ei] = h;
            out[ho + (size_t)BB * HH + em * HH + u0 + ei] = cst;
        }
    }
}

extern "C" void kernel_launch(void* const* d_in, const int* in_sizes, int n_in,
                              void* d_out, int out_size, void* d_ws, size_t ws_size,
                              hipStream_t stream) {
    const float* x  = nullptr;
    const float* W  = nullptr;
    const float* b  = nullptr;
    const float* h0 = nullptr;
    const float* c0 = nullptr;
    for (int i = 0; i < n_in; ++i) {
        int sz = in_sizes[i];
        if      (sz == BB * TT * DD)       x = (const float*)d_in[i];
        else if (sz == (DD + HH) * 4 * HH) W = (const float*)d_in[i];
        else if (sz == 4 * HH)             b = (const float*)d_in[i];
        else if (sz == BB * HH) { if (!h0) h0 = (const float*)d_in[i];
                                  else     c0 = (const float*)d_in[i]; }
    }
    float* out = (float*)d_out;
    unsigned* hhi   = (unsigned*)d_ws;                 // 2 * 8192 u32
    unsigned* hlo   = hhi + 2 * (BB * HH / 2);         // 2 * 8192 u32
    unsigned* flags = hlo + 2 * (BB * HH / 2);         // 64 * 16 u32

    lstm_init<<<64, NTHR, 0, stream>>>(h0, hhi, hlo, flags);
    lstm_scan<<<NWG, NTHR, 0, stream>>>(x, W, b, c0, out, hhi, hlo, flags);
}

// Round 11
// 16177.864 us; speedup vs baseline: 2.5284x; 2.5284x over previous
//
#include <hip/hip_runtime.h>

#define TT 2048
#define BB 32
#define DD 512
#define HH 512
#define NWG 64
#define NTHR 256

typedef short s8v __attribute__((ext_vector_type(8)));
typedef float f4v __attribute__((ext_vector_type(4)));
typedef unsigned u4v __attribute__((ext_vector_type(4)));

union UF { u4v u; s8v s; };

__device__ __forceinline__ float asf(unsigned u) { return __uint_as_float(u); }

// v_cvt_pk_bf16_f32: D[15:0]=bf16(a) RNE, D[31:16]=bf16(b)
__device__ __forceinline__ unsigned cvtpk(float a, float b) {
    unsigned r;
    asm("v_cvt_pk_bf16_f32 %0, %1, %2" : "=v"(r) : "v"(a), "v"(b));
    return r;
}
// split pair (a,b) -> hi-packed u32 and lo-packed u32 (a ~= hi+lo to ~2^-16 rel)
__device__ __forceinline__ void split2(float a, float b, unsigned& hp, unsigned& lp) {
    hp = cvtpk(a, b);
    lp = cvtpk(a - asf(hp << 16), b - asf(hp & 0xFFFF0000u));
}

// ws layout (bytes): [0) hhi 64K | [64K) hlo 64K | [128K) cbuf 64K | [192K) flags 4K | [196K+4K) xg chunk
__global__ void lstm_init(const float* __restrict__ h0, const float* __restrict__ c0,
                          unsigned* __restrict__ hhi, unsigned* __restrict__ hlo,
                          float* __restrict__ cbuf, unsigned* __restrict__ flags) {
    int j = blockIdx.x * blockDim.x + threadIdx.x;   // 0..16383
    if (j < NWG * 16) flags[j] = 0u;
    if (j < BB * HH / 2) {
        unsigned hp, lp;
        split2(h0[2 * j], h0[2 * j + 1], hp, lp);
        hhi[j] = hp;
        hlo[j] = lp;
    }
    cbuf[j] = c0[j];
}

// Phase 1: xg[i][wg][32 rows=batch][32 cols=gatecol] = x_t @ Wx + bias   (i = t - t0)
__global__ __launch_bounds__(NTHR) void gemm_xg(
    const float* __restrict__ x, const float* __restrict__ W,
    const float* __restrict__ bias, float* __restrict__ xg, int t0)
{
    const int wg  = blockIdx.x & 63;
    const int tcb = blockIdx.x >> 6;     // 64-step block within chunk
    const int tid = threadIdx.x;
    const int u0  = wg * 8;
    const int wv  = tid >> 6, ln = tid & 63;
    const int bh  = wv >> 1, ch = wv & 1;
    const int fl  = ln & 15, fg = ln >> 4;

    // Wx slice -> registers (hi/lo): frag it covers rows it*32 + fg*8 + (0..7)
    s8v whi[16], wlo[16];
    const int col  = ch * 16 + fl;
    const int wcol = ((col >> 3) << 9) + u0 + (col & 7);
    #pragma unroll
    for (int it = 0; it < 16; ++it) {
        float v[8];
        #pragma unroll
        for (int j = 0; j < 8; ++j)
            v[j] = W[(size_t)(it * 32 + fg * 8 + j) * 2048 + wcol];
        UF H, L;
        #pragma unroll
        for (int q = 0; q < 4; ++q) {
            unsigned hp, lp;
            split2(v[2 * q], v[2 * q + 1], hp, lp);
            H.u[q] = hp; L.u[q] = lp;
        }
        whi[it] = H.s; wlo[it] = L.s;
    }
    const float bcol = bias[wcol];

    const int arow = bh * 16 + fl;
    const float* xlane = x + (size_t)arow * TT * DD + fg * 8;

    for (int ii = 0; ii < 64; ++ii) {
        const int i = tcb * 64 + ii;         // chunk-local step
        const int t = t0 + i;
        f4v acc  = {0.f, 0.f, 0.f, 0.f};
        f4v accl = {0.f, 0.f, 0.f, 0.f};
        const float* xs = xlane + (size_t)t * DD;
        #pragma unroll
        for (int it = 0; it < 16; ++it) {
            float4 f0 = *(const float4*)(xs + it * 32);
            float4 f1 = *(const float4*)(xs + it * 32 + 4);
            UF H, L;
            unsigned hp, lp;
            split2(f0.x, f0.y, hp, lp); H.u[0] = hp; L.u[0] = lp;
            split2(f0.z, f0.w, hp, lp); H.u[1] = hp; L.u[1] = lp;
            split2(f1.x, f1.y, hp, lp); H.u[2] = hp; L.u[2] = lp;
            split2(f1.z, f1.w, hp, lp); H.u[3] = hp; L.u[3] = lp;
            acc  = __builtin_amdgcn_mfma_f32_16x16x32_bf16(H.s, whi[it], acc, 0, 0, 0);
            accl = __builtin_amdgcn_mfma_f32_16x16x32_bf16(L.s, whi[it], accl, 0, 0, 0);
            accl = __builtin_amdgcn_mfma_f32_16x16x32_bf16(H.s, wlo[it], accl, 0, 0, 0);
        }
        float* dst = xg + ((size_t)i * NWG + wg) * 1024;
        #pragma unroll
        for (int r = 0; r < 4; ++r)
            dst[(bh * 16 + fg * 4 + r) * 32 + ch * 16 + fl] = acc[r] + accl[r] + bcol;
    }
}

// Phase 2: persistent scan over a chunk [t0, t0+nt)
__global__ __launch_bounds__(NTHR, 1) void lstm_scan(
    const float* __restrict__ W,     // rows 512..1023 = Wh
    const float* __restrict__ xg,    // chunk-local [i][wg][32][32]
    float* __restrict__ out,
    unsigned* hhi, unsigned* hlo,    // cross-WG shared
    float* __restrict__ cbuf,
    unsigned* flags, int t0, int nt)
{
    __shared__ float P[32][33];

    const int wg  = blockIdx.x;
    const int tid = threadIdx.x;
    const int u0  = wg * 8;
    const int wv  = tid >> 6, ln = tid & 63;
    const int bh  = wv >> 1, ch = wv & 1;
    const int fl  = ln & 15, fg = ln >> 4;

    // Wh slice -> registers (hi/lo): frag it covers rows 512 + it*32 + fg*8 + (0..7)
    s8v whi[16], wlo[16];
    {
        const int col  = ch * 16 + fl;
        const int wcol = ((col >> 3) << 9) + u0 + (col & 7);
        #pragma unroll
        for (int it = 0; it < 16; ++it) {
            float v[8];
            #pragma unroll
            for (int j = 0; j < 8; ++j)
                v[j] = W[(size_t)(512 + it * 32 + fg * 8 + j) * 2048 + wcol];
            UF H, L;
            #pragma unroll
            for (int q = 0; q < 4; ++q) {
                unsigned hp, lp;
                split2(v[2 * q], v[2 * q + 1], hp, lp);
                H.u[q] = hp; L.u[q] = lp;
            }
            whi[it] = H.s; wlo[it] = L.s;
        }
    }

    const int em = tid >> 3, ei = tid & 7;
    float cst = cbuf[em * HH + u0 + ei];

    const int arow = bh * 16 + fl;
    const int hb   = arow * (HH / 2) + fg * 4;
    const int crow = bh * 16 + fg * 4;           // C-tile row base this lane
    const int ccol = ch * 16 + fl;

    for (int i = 0; i < nt; ++i) {
        const int t = t0 + i;

        // xg loads first: no h dependency, fully hidden under the poll
        float xgv[4];
        {
            const float* src = xg + ((size_t)i * NWG + wg) * 1024 + crow * 32 + ccol;
            #pragma unroll
            for (int r = 0; r < 4; ++r) xgv[r] = src[r * 32];
        }

        // wait for h_t from all WGs
        if (t > 0) {
            if (tid < 64) {
                for (;;) {
                    unsigned v = __hip_atomic_load(&flags[tid * 16], __ATOMIC_RELAXED,
                                                   __HIP_MEMORY_SCOPE_AGENT);
                    if (__all((int)v >= t)) break;
                }
            }
            __syncthreads();
            __builtin_amdgcn_fence(__ATOMIC_ACQUIRE, "agent");
        }

        // h contribution
        f4v acc  = {0.f, 0.f, 0.f, 0.f};
        f4v accl = {0.f, 0.f, 0.f, 0.f};
        {
            const unsigned* hh = hhi + (size_t)(t & 1) * (BB * HH / 2);
            const unsigned* hl = hlo + (size_t)(t & 1) * (BB * HH / 2);
            #pragma unroll
            for (int it = 0; it < 16; ++it) {
                UF H, L;
                H.u = *(const u4v*)(hh + hb + it * 16);
                L.u = *(const u4v*)(hl + hb + it * 16);
                acc  = __builtin_amdgcn_mfma_f32_16x16x32_bf16(H.s, whi[it], acc, 0, 0, 0);
                accl = __builtin_amdgcn_mfma_f32_16x16x32_bf16(L.s, whi[it], accl, 0, 0, 0);
                accl = __builtin_amdgcn_mfma_f32_16x16x32_bf16(H.s, wlo[it], accl, 0, 0, 0);
            }
        }

        #pragma unroll
        for (int r = 0; r < 4; ++r)
            P[crow + r][ccol] = acc[r] + accl[r] + xgv[r];
        __syncthreads();

        // cell (bias already folded into xg)
        float gi = P[em][ei];
        float gf = P[em][8 + ei];
        float gg = P[em][16 + ei];
        float go = P[em][24 + ei];
        float si = 1.0f / (1.0f + __expf(-gi));
        float sf = 1.0f / (1.0f + __expf(-gf));
        float e2 = __expf(2.0f * fminf(fmaxf(gg, -15.f), 15.f));
        float tg = (e2 - 1.0f) / (e2 + 1.0f);
        float so = 1.0f / (1.0f + __expf(-go));
        cst = sf * cst + si * tg;
        float e2c = __expf(2.0f * fminf(fmaxf(cst, -15.f), 15.f));
        float h = so * (e2c - 1.0f) / (e2c + 1.0f);

        // publish h_{t+1} first (critical path)
        {
            float hn = __shfl_down(h, 1);
            if ((ei & 1) == 0) {
                unsigned hp, lp;
                split2(h, hn, hp, lp);
                int idx = em * (HH / 2) + ((u0 + ei) >> 1);
                unsigned* dh = hhi + (size_t)((t + 1) & 1) * (BB * HH / 2);
                unsigned* dl = hlo + (size_t)((t + 1) & 1) * (BB * HH / 2);
                __hip_atomic_store(&dh[idx], hp, __ATOMIC_RELAXED, __HIP_MEMORY_SCOPE_AGENT);
                __hip_atomic_store(&dl[idx], lp, __ATOMIC_RELAXED, __HIP_MEMORY_SCOPE_AGENT);
            }
        }
        __syncthreads();   // vmcnt(0) drain: h stores committed before flag
        if (tid == 0)
            __hip_atomic_store(&flags[wg * 16], (unsigned)(t + 1),
                               __ATOMIC_RELAXED, __HIP_MEMORY_SCOPE_AGENT);

        // outputs off the critical path
        out[(size_t)em * TT * HH + (size_t)t * HH + u0 + ei] = h;
        if (t == TT - 1) {
            size_t ho = (size_t)BB * TT * HH;
            out[ho + em * HH + u0 + ei] = h;
            out[ho + (size_t)BB * HH + em * HH + u0 + ei] = cst;
        }
    }

    // checkpoint c for the next chunk
    cbuf[em * HH + u0 + ei] = cst;
}

extern "C" void kernel_launch(void* const* d_in, const int* in_sizes, int n_in,
                              void* d_out, int out_size, void* d_ws, size_t ws_size,
                              hipStream_t stream) {
    const float* x  = nullptr;
    const float* W  = nullptr;
    const float* b  = nullptr;
    const float* h0 = nullptr;
    const float* c0 = nullptr;
    for (int i = 0; i < n_in; ++i) {
        int sz = in_sizes[i];
        if      (sz == BB * TT * DD)       x = (const float*)d_in[i];
        else if (sz == (DD + HH) * 4 * HH) W = (const float*)d_in[i];
        else if (sz == 4 * HH)             b = (const float*)d_in[i];
        else if (sz == BB * HH) { if (!h0) h0 = (const float*)d_in[i];
                                  else     c0 = (const float*)d_in[i]; }
    }
    float* out = (float*)d_out;

    char* base = (char*)d_ws;
    unsigned* hhi   = (unsigned*)(base);            // 64 KB
    unsigned* hlo   = (unsigned*)(base + 65536);    // 64 KB
    float*    cbuf  = (float*)   (base + 131072);   // 64 KB
    unsigned* flags = (unsigned*)(base + 196608);   // 4 KB
    float*    xg    = (float*)   (base + 200704);

    // chunk length: as many 64-step blocks of xg (256 KB each) as ws allows
    size_t avail = (ws_size > 200704) ? ws_size - 200704 : 0;
    size_t maxT  = avail / (NWG * BB * 32 * sizeof(float));   // 262144 B per step
    int Tc = (int)((maxT / 64) * 64);
    if (Tc > TT) Tc = TT;
    if (Tc < 64) Tc = 64;   // minimum chunk (16 MB)

    lstm_init<<<64, NTHR, 0, stream>>>(h0, c0, hhi, hlo, cbuf, flags);

    for (int t0 = 0; t0 < TT; t0 += Tc) {
        int nt = (TT - t0 < Tc) ? (TT - t0) : Tc;
        gemm_xg<<<(nt / 64) * 64, NTHR, 0, stream>>>(x, W, b, xg, t0);
        lstm_scan<<<NWG, NTHR, 0, stream>>>(W, xg, out, hhi, hlo, cbuf, flags, t0, nt);
    }
}